// Round 1
// baseline (332.779 us; speedup 1.0000x reference)
//
#include <hip/hip_runtime.h>
#include <math.h>

#define TSZ 2048
#define CDIM 1024

typedef __attribute__((ext_vector_type(8))) short s16x8;
typedef __attribute__((ext_vector_type(4))) float f32x4;

__device__ __forceinline__ short f2bf(float f) {
    union { float f; unsigned u; } v; v.f = f;
    unsigned r = v.u + 0x7fffu + ((v.u >> 16) & 1u);   // RNE
    return (short)(r >> 16);
}

// ---------------- cast ----------------
__global__ void cast_f32_bf16(const float* __restrict__ src, short* __restrict__ dst, int n4) {
    int i = blockIdx.x * blockDim.x + threadIdx.x;
    int stride = gridDim.x * blockDim.x;
    for (; i < n4; i += stride) {
        float4 v = reinterpret_cast<const float4*>(src)[i];
        short4 o;
        o.x = f2bf(v.x); o.y = f2bf(v.y); o.z = f2bf(v.z); o.w = f2bf(v.w);
        reinterpret_cast<short4*>(dst)[i] = o;
    }
}

// ---------------- LDS staging (global_load_lds, pre-swizzled source) ----------------
// LDS tile rows of 128B (64 bf16). XOR swizzle: 16B chunk col ^= (row&7).
// gload_lds writes linearly, so we swizzle the SOURCE address (involution).
__device__ __forceinline__ void gload16(const short* g, short* l) {
    __builtin_amdgcn_global_load_lds((const __attribute__((address_space(1))) void*)g,
                                     (__attribute__((address_space(3))) void*)l, 16, 0, 0);
}

// 128 rows x 64 cols bf16 tile (GEMM A/B tiles): 1024 chunks, 4 issues/thread
__device__ __forceinline__ void stage128x64(short* lds_t, const short* g, int ld, int tid, int w) {
    #pragma unroll
    for (int call = 0; call < 4; ++call) {
        int c = call * 256 + tid;
        int row = c >> 3;
        int sc = (c & 7) ^ (row & 7);
        gload16(g + (size_t)row * ld + sc * 8, lds_t + (size_t)(call * 256 + w * 64) * 8);
    }
}

// 64 rows x 64 cols bf16 tile (attention K/Kp/Vt tiles): 512 chunks, 2 issues/thread
__device__ __forceinline__ void stage64x64(short* lds_t, const short* g, int ld, int tid, int w) {
    #pragma unroll
    for (int call = 0; call < 2; ++call) {
        int c = call * 256 + tid;
        int row = c >> 3;
        int sc = (c & 7) ^ (row & 7);
        gload16(g + (size_t)row * ld + sc * 8, lds_t + (size_t)(call * 256 + w * 64) * 8);
    }
}

// read one MFMA fragment (8 bf16) from swizzled tile: row, 16B-chunk kc (0..7)
__device__ __forceinline__ s16x8 frag_read(const short* tile, int row, int kc) {
    const char* p = (const char*)tile + row * 128 + (((kc ^ (row & 7)) & 7) << 4);
    return *reinterpret_cast<const s16x8*>(p);
}

// ---------------- projection GEMM: C = A(4096x1024) * W^T, 4 weights ----------------
__global__ __launch_bounds__(256) void gemm4_proj(
    const short* __restrict__ xb,
    const short* __restrict__ w0, const short* __restrict__ w1,
    const short* __restrict__ w2, const short* __restrict__ w3,
    short* __restrict__ o0, short* __restrict__ o1,
    short* __restrict__ o2, short* __restrict__ o3)
{
    __shared__ short sA[128 * 64], sB[128 * 64];
    int tid = threadIdx.x, lane = tid & 63, w = tid >> 6;
    int wrow = w >> 1, wcol = w & 1;
    int z = blockIdx.y;
    const short* W = z == 0 ? w0 : z == 1 ? w1 : z == 2 ? w2 : w3;
    short* outp = z == 0 ? o0 : z == 1 ? o1 : z == 2 ? o2 : o3;
    int r0 = (blockIdx.x >> 3) * 128;
    int c0 = (blockIdx.x & 7) * 128;

    f32x4 zero = {0.f, 0.f, 0.f, 0.f};
    f32x4 acc[4][4];
    #pragma unroll
    for (int i = 0; i < 4; ++i)
        #pragma unroll
        for (int j = 0; j < 4; ++j) acc[i][j] = zero;

    for (int kt = 0; kt < 16; ++kt) {
        __syncthreads();
        stage128x64(sA, xb + (size_t)r0 * CDIM + kt * 64, CDIM, tid, w);
        stage128x64(sB, W + (size_t)c0 * CDIM + kt * 64, CDIM, tid, w);
        __syncthreads();
        #pragma unroll
        for (int ks = 0; ks < 2; ++ks) {
            int kc = ks * 4 + (lane >> 4);
            s16x8 af[4], bfr[4];
            #pragma unroll
            for (int mt = 0; mt < 4; ++mt) af[mt] = frag_read(sA, wrow * 64 + mt * 16 + (lane & 15), kc);
            #pragma unroll
            for (int nt = 0; nt < 4; ++nt) bfr[nt] = frag_read(sB, wcol * 64 + nt * 16 + (lane & 15), kc);
            #pragma unroll
            for (int mt = 0; mt < 4; ++mt)
                #pragma unroll
                for (int nt = 0; nt < 4; ++nt)
                    acc[mt][nt] = __builtin_amdgcn_mfma_f32_16x16x32_bf16(af[mt], bfr[nt], acc[mt][nt], 0, 0, 0);
        }
    }

    bool vt_mode = (z == 2);
    #pragma unroll
    for (int mt = 0; mt < 4; ++mt)
        #pragma unroll
        for (int nt = 0; nt < 4; ++nt)
            #pragma unroll
            for (int jr = 0; jr < 4; ++jr) {
                int gi = r0 + wrow * 64 + mt * 16 + ((lane >> 4) << 2) + jr;  // row in [0,4096)
                int gn = c0 + wcol * 64 + nt * 16 + (lane & 15);              // col in [0,1024)
                short v = f2bf(acc[mt][nt][jr]);
                int b = gi >> 11, t = gi & 2047, h = gn >> 6, d = gn & 63;
                size_t off;
                if (!vt_mode) off = ((size_t)(b * 16 + h) * TSZ + t) * 64 + d;   // (B,H,T,D)
                else          off = ((size_t)(b * 16 + h) * 64 + d) * TSZ + t;   // (B,H,D,T)
                outp[off] = v;
            }
}

// ---------------- final GEMM: out(f32) = attn(4096x1024 bf16) * Wo^T ----------------
__global__ __launch_bounds__(256) void gemm_final(
    const short* __restrict__ ab, const short* __restrict__ wo, float* __restrict__ out)
{
    __shared__ short sA[128 * 64], sB[128 * 64];
    int tid = threadIdx.x, lane = tid & 63, w = tid >> 6;
    int wrow = w >> 1, wcol = w & 1;
    int r0 = (blockIdx.x >> 3) * 128;
    int c0 = (blockIdx.x & 7) * 128;

    f32x4 zero = {0.f, 0.f, 0.f, 0.f};
    f32x4 acc[4][4];
    #pragma unroll
    for (int i = 0; i < 4; ++i)
        #pragma unroll
        for (int j = 0; j < 4; ++j) acc[i][j] = zero;

    for (int kt = 0; kt < 16; ++kt) {
        __syncthreads();
        stage128x64(sA, ab + (size_t)r0 * CDIM + kt * 64, CDIM, tid, w);
        stage128x64(sB, wo + (size_t)c0 * CDIM + kt * 64, CDIM, tid, w);
        __syncthreads();
        #pragma unroll
        for (int ks = 0; ks < 2; ++ks) {
            int kc = ks * 4 + (lane >> 4);
            s16x8 af[4], bfr[4];
            #pragma unroll
            for (int mt = 0; mt < 4; ++mt) af[mt] = frag_read(sA, wrow * 64 + mt * 16 + (lane & 15), kc);
            #pragma unroll
            for (int nt = 0; nt < 4; ++nt) bfr[nt] = frag_read(sB, wcol * 64 + nt * 16 + (lane & 15), kc);
            #pragma unroll
            for (int mt = 0; mt < 4; ++mt)
                #pragma unroll
                for (int nt = 0; nt < 4; ++nt)
                    acc[mt][nt] = __builtin_amdgcn_mfma_f32_16x16x32_bf16(af[mt], bfr[nt], acc[mt][nt], 0, 0, 0);
        }
    }

    #pragma unroll
    for (int mt = 0; mt < 4; ++mt)
        #pragma unroll
        for (int nt = 0; nt < 4; ++nt)
            #pragma unroll
            for (int jr = 0; jr < 4; ++jr) {
                int gi = r0 + wrow * 64 + mt * 16 + ((lane >> 4) << 2) + jr;
                int gn = c0 + wcol * 64 + nt * 16 + (lane & 15);
                out[(size_t)gi * CDIM + gn] = acc[mt][nt][jr];
            }
}

// ---------------- fused dual-branch flash attention ----------------
__device__ __forceinline__ void attn_branch(
    const s16x8* qf, const short* sK, const short* sV, short* sP,
    f32x4* o, float* m, float* lsum, int lane)
{
    f32x4 zero = {0.f, 0.f, 0.f, 0.f};
    f32x4 st[4];
    #pragma unroll
    for (int ct = 0; ct < 4; ++ct) st[ct] = zero;

    // S = Q * K^T (16 q-rows x 64 keys), K-dim = d = 64
    #pragma unroll
    for (int ks = 0; ks < 2; ++ks) {
        int kc = ks * 4 + (lane >> 4);
        s16x8 kf[4];
        #pragma unroll
        for (int ct = 0; ct < 4; ++ct) kf[ct] = frag_read(sK, ct * 16 + (lane & 15), kc);
        #pragma unroll
        for (int ct = 0; ct < 4; ++ct)
            st[ct] = __builtin_amdgcn_mfma_f32_16x16x32_bf16(qf[ks], kf[ct], st[ct], 0, 0, 0);
    }
    #pragma unroll
    for (int ct = 0; ct < 4; ++ct) st[ct] = st[ct] * 0.125f;   // 1/sqrt(64)

    // online softmax: lane holds rows r=(lane>>4)*4+jr, cols ct*16+(lane&15)
    float rmax[4], pexp[4][4], scl[4], psum[4];
    #pragma unroll
    for (int jr = 0; jr < 4; ++jr)
        rmax[jr] = fmaxf(fmaxf(st[0][jr], st[1][jr]), fmaxf(st[2][jr], st[3][jr]));
    #pragma unroll
    for (int off = 1; off < 16; off <<= 1)
        #pragma unroll
        for (int jr = 0; jr < 4; ++jr)
            rmax[jr] = fmaxf(rmax[jr], __shfl_xor(rmax[jr], off, 64));
    #pragma unroll
    for (int jr = 0; jr < 4; ++jr) {
        float mn = fmaxf(m[jr], rmax[jr]);
        scl[jr] = __expf(m[jr] - mn);
        m[jr] = mn;
    }
    #pragma unroll
    for (int ct = 0; ct < 4; ++ct)
        #pragma unroll
        for (int jr = 0; jr < 4; ++jr)
            pexp[ct][jr] = __expf(st[ct][jr] - m[jr]);
    #pragma unroll
    for (int jr = 0; jr < 4; ++jr)
        psum[jr] = (pexp[0][jr] + pexp[1][jr]) + (pexp[2][jr] + pexp[3][jr]);
    #pragma unroll
    for (int off = 1; off < 16; off <<= 1)
        #pragma unroll
        for (int jr = 0; jr < 4; ++jr)
            psum[jr] += __shfl_xor(psum[jr], off, 64);
    #pragma unroll
    for (int jr = 0; jr < 4; ++jr) lsum[jr] = lsum[jr] * scl[jr] + psum[jr];
    #pragma unroll
    for (int nt = 0; nt < 4; ++nt)
        #pragma unroll
        for (int jr = 0; jr < 4; ++jr)
            o[nt][jr] *= scl[jr];

    // P -> wave-private LDS (swizzled [16][64] bf16)
    #pragma unroll
    for (int ct = 0; ct < 4; ++ct)
        #pragma unroll
        for (int jr = 0; jr < 4; ++jr) {
            int row = ((lane >> 4) << 2) + jr;
            int col = ct * 16 + (lane & 15);
            int byte = ((row << 7) + (col << 1)) ^ ((row & 7) << 4);
            *(short*)((char*)sP + byte) = f2bf(pexp[ct][jr]);
        }

    // O += P * V  (A = P rows q, k = keys; B = V[key][d] read from Vt rows d)
    #pragma unroll
    for (int ks = 0; ks < 2; ++ks) {
        int kc = ks * 4 + (lane >> 4);
        s16x8 pf = frag_read(sP, lane & 15, kc);
        #pragma unroll
        for (int nt = 0; nt < 4; ++nt) {
            s16x8 vf = frag_read(sV, nt * 16 + (lane & 15), kc);
            o[nt] = __builtin_amdgcn_mfma_f32_16x16x32_bf16(pf, vf, o[nt], 0, 0, 0);
        }
    }
}

__global__ __launch_bounds__(256) void attn_fused(
    const short* __restrict__ q, const short* __restrict__ k, const short* __restrict__ kp,
    const short* __restrict__ vt, const float* __restrict__ alphap, short* __restrict__ aout)
{
    __shared__ short sK[64 * 64], sKp[64 * 64], sV[64 * 64], sP[4][16 * 64];
    int tid = threadIdx.x, lane = tid & 63, w = tid >> 6;
    int bh = blockIdx.y;
    int qt0 = blockIdx.x * 64;
    const short* Q  = q  + (size_t)bh * TSZ * 64;
    const short* K  = k  + (size_t)bh * TSZ * 64;
    const short* Kp = kp + (size_t)bh * TSZ * 64;
    const short* Vt = vt + (size_t)bh * 64 * TSZ;

    int qrow = qt0 + w * 16 + (lane & 15);
    s16x8 qf[2];
    qf[0] = *reinterpret_cast<const s16x8*>(Q + (size_t)qrow * 64 + (lane >> 4) * 8);
    qf[1] = *reinterpret_cast<const s16x8*>(Q + (size_t)qrow * 64 + 32 + (lane >> 4) * 8);

    f32x4 zero = {0.f, 0.f, 0.f, 0.f};
    f32x4 o0[4], o1[4];
    float m0[4], m1[4], l0[4], l1[4];
    #pragma unroll
    for (int i = 0; i < 4; ++i) { o0[i] = zero; o1[i] = zero; }
    #pragma unroll
    for (int i = 0; i < 4; ++i) { m0[i] = -1e30f; m1[i] = -1e30f; l0[i] = 0.f; l1[i] = 0.f; }

    for (int kt = 0; kt < 32; ++kt) {
        __syncthreads();
        int t0 = kt * 64;
        stage64x64(sK,  K  + (size_t)t0 * 64, 64, tid, w);
        stage64x64(sKp, Kp + (size_t)t0 * 64, 64, tid, w);
        stage64x64(sV,  Vt + t0, TSZ, tid, w);
        __syncthreads();
        attn_branch(qf, sK,  sV, sP[w], o0, m0, l0, lane);
        attn_branch(qf, sKp, sV, sP[w], o1, m1, l1, lane);
    }

    float alpha = alphap[0];
    int b = bh >> 4, h = bh & 15;
    #pragma unroll
    for (int nt = 0; nt < 4; ++nt)
        #pragma unroll
        for (int jr = 0; jr < 4; ++jr) {
            int t = qt0 + w * 16 + ((lane >> 4) << 2) + jr;
            int col = h * 64 + nt * 16 + (lane & 15);
            float v = alpha * o0[nt][jr] / l0[jr] + (1.f - alpha) * o1[nt][jr] / l1[jr];
            aout[(size_t)(b * TSZ + t) * CDIM + col] = f2bf(v);
        }
}

// ---------------- host ----------------
extern "C" void kernel_launch(void* const* d_in, const int* in_sizes, int n_in,
                              void* d_out, int out_size, void* d_ws, size_t ws_size,
                              hipStream_t stream)
{
    const float* x     = (const float*)d_in[0];
    const float* WQ    = (const float*)d_in[1];
    const float* WK    = (const float*)d_in[2];
    const float* WV    = (const float*)d_in[3];
    const float* WKp   = (const float*)d_in[4];
    const float* WO    = (const float*)d_in[5];
    const float* alpha = (const float*)d_in[6];
    float* out = (float*)d_out;

    char* ws = (char*)d_ws;
    const size_t MB = 1024 * 1024;
    short* xb   = (short*)(ws + 0);        // 8 MB  x bf16
    short* wqb  = (short*)(ws + 8 * MB);   // 2 MB each
    short* wkb  = (short*)(ws + 10 * MB);
    short* wvb  = (short*)(ws + 12 * MB);
    short* wkpb = (short*)(ws + 14 * MB);
    short* wob  = (short*)(ws + 16 * MB);
    short* qb   = (short*)(ws + 18 * MB);  // 8 MB each, (B,H,T,D)
    short* kb   = (short*)(ws + 26 * MB);
    short* kpb  = (short*)(ws + 34 * MB);
    short* vtb  = (short*)(ws + 42 * MB);  // (B,H,D,T)
    short* anb  = (short*)(ws + 50 * MB);  // attention out, (B,T,C) bf16

    cast_f32_bf16<<<2048, 256, 0, stream>>>(x,   xb,   (TSZ * 2 * CDIM) / 4);
    cast_f32_bf16<<<1024, 256, 0, stream>>>(WQ,  wqb,  (CDIM * CDIM) / 4);
    cast_f32_bf16<<<1024, 256, 0, stream>>>(WK,  wkb,  (CDIM * CDIM) / 4);
    cast_f32_bf16<<<1024, 256, 0, stream>>>(WV,  wvb,  (CDIM * CDIM) / 4);
    cast_f32_bf16<<<1024, 256, 0, stream>>>(WKp, wkpb, (CDIM * CDIM) / 4);
    cast_f32_bf16<<<1024, 256, 0, stream>>>(WO,  wob,  (CDIM * CDIM) / 4);

    gemm4_proj<<<dim3(256, 4), 256, 0, stream>>>(xb, wqb, wkb, wvb, wkpb, qb, kb, vtb, kpb);
    attn_fused<<<dim3(32, 32), 256, 0, stream>>>(qb, kb, kpb, vtb, alpha, anb);
    gemm_final<<<dim3(256), 256, 0, stream>>>(anb, wob, out);
}

// Round 2
// 219.609 us; speedup vs baseline: 1.5153x; 1.5153x over previous
//
#include <hip/hip_runtime.h>
#include <math.h>

#define TSZ 2048
#define CDIM 1024

typedef __attribute__((ext_vector_type(8))) short s16x8;
typedef __attribute__((ext_vector_type(4))) float f32x4;
typedef __attribute__((ext_vector_type(16))) float f32x16;
typedef __attribute__((ext_vector_type(4))) unsigned int u32x4;

__device__ __forceinline__ short f2bf(float f) {
    union { float f; unsigned u; } v; v.f = f;
    unsigned r = v.u + 0x7fffu + ((v.u >> 16) & 1u);   // RNE
    return (short)(r >> 16);
}
__device__ __forceinline__ unsigned pkbf(float lo, float hi) {
    return (unsigned)(unsigned short)f2bf(lo) | ((unsigned)(unsigned short)f2bf(hi) << 16);
}
__device__ __forceinline__ s16x8 u2s(u32x4 u) {
    union { u32x4 u; s16x8 s; } c; c.u = u; return c.s;
}
__device__ __forceinline__ f32x16 mfma32(s16x8 a, s16x8 b, f32x16 c) {
    return __builtin_amdgcn_mfma_f32_32x32x16_bf16(a, b, c, 0, 0, 0);
}

// ---------------- casts ----------------
__global__ void cast_f32_bf16(const float* __restrict__ src, short* __restrict__ dst, int n4) {
    int i = blockIdx.x * blockDim.x + threadIdx.x;
    int stride = gridDim.x * blockDim.x;
    for (; i < n4; i += stride) {
        float4 v = reinterpret_cast<const float4*>(src)[i];
        short4 o;
        o.x = f2bf(v.x); o.y = f2bf(v.y); o.z = f2bf(v.z); o.w = f2bf(v.w);
        reinterpret_cast<short4*>(dst)[i] = o;
    }
}

__global__ void cast_w5(const float* __restrict__ w0, const float* __restrict__ w1,
                        const float* __restrict__ w2, const float* __restrict__ w3,
                        const float* __restrict__ w4,
                        short* __restrict__ o0, short* __restrict__ o1,
                        short* __restrict__ o2, short* __restrict__ o3,
                        short* __restrict__ o4) {
    int z = blockIdx.y;
    const float* s = z == 0 ? w0 : z == 1 ? w1 : z == 2 ? w2 : z == 3 ? w3 : w4;
    short* d = z == 0 ? o0 : z == 1 ? o1 : z == 2 ? o2 : z == 3 ? o3 : o4;
    int i = blockIdx.x * blockDim.x + threadIdx.x;   // exactly CDIM*CDIM/4 threads
    float4 v = reinterpret_cast<const float4*>(s)[i];
    short4 o;
    o.x = f2bf(v.x); o.y = f2bf(v.y); o.z = f2bf(v.z); o.w = f2bf(v.w);
    reinterpret_cast<short4*>(d)[i] = o;
}

// ---------------- LDS staging (global_load_lds, pre-swizzled source) ----------------
__device__ __forceinline__ void gload16(const short* g, short* l) {
    __builtin_amdgcn_global_load_lds((const __attribute__((address_space(1))) void*)g,
                                     (__attribute__((address_space(3))) void*)l, 16, 0, 0);
}

__device__ __forceinline__ void stage128x64(short* lds_t, const short* g, int ld, int tid, int w) {
    #pragma unroll
    for (int call = 0; call < 4; ++call) {
        int c = call * 256 + tid;
        int row = c >> 3;
        int sc = (c & 7) ^ (row & 7);
        gload16(g + (size_t)row * ld + sc * 8, lds_t + (size_t)(call * 256 + w * 64) * 8);
    }
}

__device__ __forceinline__ void stage64x64(short* lds_t, const short* g, int ld, int tid, int w) {
    #pragma unroll
    for (int call = 0; call < 2; ++call) {
        int c = call * 256 + tid;
        int row = c >> 3;
        int sc = (c & 7) ^ (row & 7);
        gload16(g + (size_t)row * ld + sc * 8, lds_t + (size_t)(call * 256 + w * 64) * 8);
    }
}

// read one MFMA fragment (8 bf16) from swizzled tile: row, 16B-chunk kc (0..7)
__device__ __forceinline__ s16x8 frag_read(const short* tile, int row, int kc) {
    const char* p = (const char*)tile + row * 128 + (((kc ^ (row & 7)) & 7) << 4);
    return *reinterpret_cast<const s16x8*>(p);
}

// ---------------- projection GEMM: C = A(4096x1024) * W^T, 4 weights ----------------
__global__ __launch_bounds__(256) void gemm4_proj(
    const short* __restrict__ xb,
    const short* __restrict__ w0, const short* __restrict__ w1,
    const short* __restrict__ w2, const short* __restrict__ w3,
    short* __restrict__ o0, short* __restrict__ o1,
    short* __restrict__ o2, short* __restrict__ o3)
{
    __shared__ short sA[128 * 64], sB[128 * 64];
    int tid = threadIdx.x, lane = tid & 63, w = tid >> 6;
    int wrow = w >> 1, wcol = w & 1;
    int z = blockIdx.y;
    const short* W = z == 0 ? w0 : z == 1 ? w1 : z == 2 ? w2 : w3;
    short* outp = z == 0 ? o0 : z == 1 ? o1 : z == 2 ? o2 : o3;
    int r0 = (blockIdx.x >> 3) * 128;
    int c0 = (blockIdx.x & 7) * 128;

    f32x4 zero = {0.f, 0.f, 0.f, 0.f};
    f32x4 acc[4][4];
    #pragma unroll
    for (int i = 0; i < 4; ++i)
        #pragma unroll
        for (int j = 0; j < 4; ++j) acc[i][j] = zero;

    for (int kt = 0; kt < 16; ++kt) {
        __syncthreads();
        stage128x64(sA, xb + (size_t)r0 * CDIM + kt * 64, CDIM, tid, w);
        stage128x64(sB, W + (size_t)c0 * CDIM + kt * 64, CDIM, tid, w);
        __syncthreads();
        #pragma unroll
        for (int ks = 0; ks < 2; ++ks) {
            int kc = ks * 4 + (lane >> 4);
            s16x8 af[4], bfr[4];
            #pragma unroll
            for (int mt = 0; mt < 4; ++mt) af[mt] = frag_read(sA, wrow * 64 + mt * 16 + (lane & 15), kc);
            #pragma unroll
            for (int nt = 0; nt < 4; ++nt) bfr[nt] = frag_read(sB, wcol * 64 + nt * 16 + (lane & 15), kc);
            #pragma unroll
            for (int mt = 0; mt < 4; ++mt)
                #pragma unroll
                for (int nt = 0; nt < 4; ++nt)
                    acc[mt][nt] = __builtin_amdgcn_mfma_f32_16x16x32_bf16(af[mt], bfr[nt], acc[mt][nt], 0, 0, 0);
        }
    }

    bool vt_mode = (z == 2);
    #pragma unroll
    for (int mt = 0; mt < 4; ++mt)
        #pragma unroll
        for (int nt = 0; nt < 4; ++nt)
            #pragma unroll
            for (int jr = 0; jr < 4; ++jr) {
                int gi = r0 + wrow * 64 + mt * 16 + ((lane >> 4) << 2) + jr;
                int gn = c0 + wcol * 64 + nt * 16 + (lane & 15);
                short v = f2bf(acc[mt][nt][jr]);
                int b = gi >> 11, t = gi & 2047, h = gn >> 6, d = gn & 63;
                size_t off;
                if (!vt_mode) off = ((size_t)(b * 16 + h) * TSZ + t) * 64 + d;   // (B,H,T,D)
                else          off = ((size_t)(b * 16 + h) * 64 + d) * TSZ + t;   // (B,H,D,T)
                outp[off] = v;
            }
}

// ---------------- final GEMM: out(f32) = attn(4096x1024 bf16) * Wo^T ----------------
__global__ __launch_bounds__(256) void gemm_final(
    const short* __restrict__ ab, const short* __restrict__ wo, float* __restrict__ out)
{
    __shared__ short sA[128 * 64], sB[128 * 64];
    int tid = threadIdx.x, lane = tid & 63, w = tid >> 6;
    int wrow = w >> 1, wcol = w & 1;
    int r0 = (blockIdx.x >> 3) * 128;
    int c0 = (blockIdx.x & 7) * 128;

    f32x4 zero = {0.f, 0.f, 0.f, 0.f};
    f32x4 acc[4][4];
    #pragma unroll
    for (int i = 0; i < 4; ++i)
        #pragma unroll
        for (int j = 0; j < 4; ++j) acc[i][j] = zero;

    for (int kt = 0; kt < 16; ++kt) {
        __syncthreads();
        stage128x64(sA, ab + (size_t)r0 * CDIM + kt * 64, CDIM, tid, w);
        stage128x64(sB, wo + (size_t)c0 * CDIM + kt * 64, CDIM, tid, w);
        __syncthreads();
        #pragma unroll
        for (int ks = 0; ks < 2; ++ks) {
            int kc = ks * 4 + (lane >> 4);
            s16x8 af[4], bfr[4];
            #pragma unroll
            for (int mt = 0; mt < 4; ++mt) af[mt] = frag_read(sA, wrow * 64 + mt * 16 + (lane & 15), kc);
            #pragma unroll
            for (int nt = 0; nt < 4; ++nt) bfr[nt] = frag_read(sB, wcol * 64 + nt * 16 + (lane & 15), kc);
            #pragma unroll
            for (int mt = 0; mt < 4; ++mt)
                #pragma unroll
                for (int nt = 0; nt < 4; ++nt)
                    acc[mt][nt] = __builtin_amdgcn_mfma_f32_16x16x32_bf16(af[mt], bfr[nt], acc[mt][nt], 0, 0, 0);
        }
    }

    #pragma unroll
    for (int mt = 0; mt < 4; ++mt)
        #pragma unroll
        for (int nt = 0; nt < 4; ++nt)
            #pragma unroll
            for (int jr = 0; jr < 4; ++jr) {
                int gi = r0 + wrow * 64 + mt * 16 + ((lane >> 4) << 2) + jr;
                int gn = c0 + wcol * 64 + nt * 16 + (lane & 15);
                out[(size_t)gi * CDIM + gn] = acc[mt][nt][jr];
            }
}

// ---------------- fused dual-branch flash attention (8-wide swapped-QK^T, 32x32 MFMA) ----
// Per wave: 32 q-rows. S^T = mfma(K, Q): C col = q (lane&31), row = key
// (reg&3)+8*(reg>>2)+4*(lane>>5). Lane holds 32 of 64 keys -> in-lane softmax +
// one cross-half shfl. P packed to bf16 in-register, fed as PV B-operand.
__global__ __launch_bounds__(256, 2) void attn_fused(
    const short* __restrict__ q, const short* __restrict__ k, const short* __restrict__ kp,
    const short* __restrict__ vt, const float* __restrict__ alphap, short* __restrict__ aout)
{
    __shared__ short sK[2][64 * 64], sKp[2][64 * 64], sV[2][64 * 64];
    int tid = threadIdx.x, lane = tid & 63, w = tid >> 6;
    int h = lane >> 5, l31 = lane & 31;
    int bh = blockIdx.y;
    int qt0 = blockIdx.x * 128;
    const short* Q  = q  + (size_t)bh * TSZ * 64;
    const short* K  = k  + (size_t)bh * TSZ * 64;
    const short* Kp = kp + (size_t)bh * TSZ * 64;
    const short* Vt = vt + (size_t)bh * 64 * TSZ;

    // Q frags: B-operand B[q][d], lane owns q = l31; step s covers d = 16s + 8h + j
    int qrow = qt0 + w * 32 + l31;
    s16x8 qf[4];
    #pragma unroll
    for (int s = 0; s < 4; ++s)
        qf[s] = *reinterpret_cast<const s16x8*>(Q + (size_t)qrow * 64 + s * 16 + h * 8);

    f32x16 o[2][2];
    #pragma unroll
    for (int br = 0; br < 2; ++br)
        #pragma unroll
        for (int dt = 0; dt < 2; ++dt)
            #pragma unroll
            for (int r = 0; r < 16; ++r) o[br][dt][r] = 0.f;
    float m[2] = {-1e30f, -1e30f}, lsum[2] = {0.f, 0.f};
    const float SCL = 0.125f;  // 1/sqrt(64)

    // prologue: stage tile 0
    stage64x64(sK[0],  K, 64, tid, w);
    stage64x64(sKp[0], Kp, 64, tid, w);
    stage64x64(sV[0],  Vt, TSZ, tid, w);
    __syncthreads();

    int cur = 0;
    for (int kt = 0; kt < 32; ++kt) {
        // issue next tile's loads; they fly during this tile's compute
        if (kt < 31) {
            int t0n = (kt + 1) * 64;
            stage64x64(sK[cur ^ 1],  K  + (size_t)t0n * 64, 64, tid, w);
            stage64x64(sKp[cur ^ 1], Kp + (size_t)t0n * 64, 64, tid, w);
            stage64x64(sV[cur ^ 1],  Vt + t0n, TSZ, tid, w);
        }
        const short* kbuf0 = sK[cur];
        const short* kbuf1 = sKp[cur];
        const short* vbuf  = sV[cur];

        u32x4 pfrag[2][4];
        #pragma unroll
        for (int br = 0; br < 2; ++br) {
            const short* kb = br == 0 ? kbuf0 : kbuf1;
            f32x16 sa0, sa1;
            #pragma unroll
            for (int r = 0; r < 16; ++r) { sa0[r] = 0.f; sa1[r] = 0.f; }
            #pragma unroll
            for (int s = 0; s < 4; ++s) {
                s16x8 af0 = frag_read(kb, l31,      2 * s + h);
                s16x8 af1 = frag_read(kb, 32 + l31, 2 * s + h);
                sa0 = mfma32(af0, qf[s], sa0);
                sa1 = mfma32(af1, qf[s], sa1);
            }
            // in-lane softmax over 32 held keys + one cross-half exchange
            float pmax = -1e30f;
            #pragma unroll
            for (int r = 0; r < 16; ++r) pmax = fmaxf(pmax, fmaxf(sa0[r], sa1[r]));
            pmax = fmaxf(pmax, __shfl_xor(pmax, 32, 64));
            float mnew = fmaxf(m[br], pmax);
            float scl = __expf((m[br] - mnew) * SCL);
            m[br] = mnew;
            float psum = 0.f;
            #pragma unroll
            for (int r = 0; r < 16; ++r) {
                sa0[r] = __expf((sa0[r] - mnew) * SCL); psum += sa0[r];
                sa1[r] = __expf((sa1[r] - mnew) * SCL); psum += sa1[r];
            }
            psum += __shfl_xor(psum, 32, 64);
            lsum[br] = lsum[br] * scl + psum;
            #pragma unroll
            for (int dt = 0; dt < 2; ++dt)
                #pragma unroll
                for (int r = 0; r < 16; ++r) o[br][dt][r] *= scl;

            // pack P to bf16 B-frags. tile t keys 32t+: own keys (r&3)+8(r>>2)+4h.
            #pragma unroll
            for (int t = 0; t < 2; ++t) {
                unsigned pk[8], xk[8];
                #pragma unroll
                for (int i = 0; i < 8; ++i)
                    pk[i] = t == 0 ? pkbf(sa0[2 * i], sa0[2 * i + 1])
                                   : pkbf(sa1[2 * i], sa1[2 * i + 1]);
                #pragma unroll
                for (int i = 0; i < 8; ++i)
                    xk[i] = (unsigned)__shfl_xor((int)pk[i], 32, 64);
                u32x4 fA, fB;   // steps 2t (keys 32t+0..15) and 2t+1 (keys 32t+16..31)
                fA[0] = h ? xk[2] : pk[0];  fA[1] = h ? xk[3] : pk[1];
                fA[2] = h ? pk[2] : xk[0];  fA[3] = h ? pk[3] : xk[1];
                fB[0] = h ? xk[6] : pk[4];  fB[1] = h ? xk[7] : pk[5];
                fB[2] = h ? pk[6] : xk[4];  fB[3] = h ? pk[7] : xk[5];
                pfrag[br][2 * t] = fA;
                pfrag[br][2 * t + 1] = fB;
            }
        }

        // PV: O^T[d][q] += V^T[d][key] * P[q][key]; V-frags shared by both branches
        #pragma unroll
        for (int s = 0; s < 4; ++s)
            #pragma unroll
            for (int dt = 0; dt < 2; ++dt) {
                s16x8 vf = frag_read(vbuf, dt * 32 + l31, 2 * s + h);
                o[0][dt] = mfma32(vf, u2s(pfrag[0][s]), o[0][dt]);
                o[1][dt] = mfma32(vf, u2s(pfrag[1][s]), o[1][dt]);
            }

        __syncthreads();   // drain next-tile loads (overlapped) + buffer-reuse barrier
        cur ^= 1;
    }

    // epilogue: out[q][d] = alpha*o0/l0 + (1-alpha)*o1/l1, written to (B,T,C)
    float alpha = alphap[0];
    float a0 = alpha / lsum[0];
    float a1 = (1.f - alpha) / lsum[1];
    int b = bh >> 4, hh = bh & 15;
    int t = qt0 + w * 32 + l31;
    size_t rowbase = ((size_t)(b * TSZ + t)) * CDIM + hh * 64;
    #pragma unroll
    for (int dt = 0; dt < 2; ++dt)
        #pragma unroll
        for (int g = 0; g < 4; ++g) {
            short4 v4;
            #pragma unroll
            for (int j = 0; j < 4; ++j) {
                int r = 4 * g + j;   // d = j + 8g + 4h + 32dt
                float v = a0 * o[0][dt][r] + a1 * o[1][dt][r];
                ((short*)&v4)[j] = f2bf(v);
            }
            *reinterpret_cast<short4*>(aout + rowbase + dt * 32 + g * 8 + h * 4) = v4;
        }
}

// ---------------- host ----------------
extern "C" void kernel_launch(void* const* d_in, const int* in_sizes, int n_in,
                              void* d_out, int out_size, void* d_ws, size_t ws_size,
                              hipStream_t stream)
{
    const float* x     = (const float*)d_in[0];
    const float* WQ    = (const float*)d_in[1];
    const float* WK    = (const float*)d_in[2];
    const float* WV    = (const float*)d_in[3];
    const float* WKp   = (const float*)d_in[4];
    const float* WO    = (const float*)d_in[5];
    const float* alpha = (const float*)d_in[6];
    float* out = (float*)d_out;

    char* ws = (char*)d_ws;
    const size_t MB = 1024 * 1024;
    short* xb   = (short*)(ws + 0);        // 8 MB  x bf16
    short* wqb  = (short*)(ws + 8 * MB);   // 2 MB each
    short* wkb  = (short*)(ws + 10 * MB);
    short* wvb  = (short*)(ws + 12 * MB);
    short* wkpb = (short*)(ws + 14 * MB);
    short* wob  = (short*)(ws + 16 * MB);
    short* qb   = (short*)(ws + 18 * MB);  // 8 MB each, (B,H,T,D)
    short* kb   = (short*)(ws + 26 * MB);
    short* kpb  = (short*)(ws + 34 * MB);
    short* vtb  = (short*)(ws + 42 * MB);  // (B,H,D,T)
    short* anb  = (short*)(ws + 50 * MB);  // attention out, (B,T,C) bf16

    cast_f32_bf16<<<2048, 256, 0, stream>>>(x, xb, (TSZ * 2 * CDIM) / 4);
    cast_w5<<<dim3(1024, 5), 256, 0, stream>>>(WQ, WK, WV, WKp, WO,
                                               wqb, wkb, wvb, wkpb, wob);

    gemm4_proj<<<dim3(256, 4), 256, 0, stream>>>(xb, wqb, wkb, wvb, wkpb, qb, kb, vtb, kpb);
    attn_fused<<<dim3(16, 32), 256, 0, stream>>>(qb, kb, kpb, vtb, alpha, anb);
    gemm_final<<<dim3(256), 256, 0, stream>>>(anb, wob, out);
}

// Round 3
// 193.448 us; speedup vs baseline: 1.7202x; 1.1352x over previous
//
#include <hip/hip_runtime.h>
#include <math.h>

#define TSZ 2048
#define CDIM 1024

typedef __attribute__((ext_vector_type(8))) short s16x8;
typedef __attribute__((ext_vector_type(4))) float f32x4;
typedef __attribute__((ext_vector_type(16))) float f32x16;
typedef __attribute__((ext_vector_type(2))) unsigned int u32x2;
typedef __attribute__((ext_vector_type(4))) unsigned int u32x4;

__device__ __forceinline__ short f2bf(float f) {
    union { float f; unsigned u; } v; v.f = f;
    unsigned r = v.u + 0x7fffu + ((v.u >> 16) & 1u);   // RNE
    return (short)(r >> 16);
}
__device__ __forceinline__ unsigned cvtpk(float lo, float hi) {
    unsigned r;
    asm("v_cvt_pk_bf16_f32 %0, %1, %2" : "=v"(r) : "v"(lo), "v"(hi));
    return r;
}
__device__ __forceinline__ s16x8 u2s(u32x4 u) {
    union { u32x4 u; s16x8 s; } c; c.u = u; return c.s;
}
__device__ __forceinline__ f32x16 mfma32(s16x8 a, s16x8 b, f32x16 c) {
    return __builtin_amdgcn_mfma_f32_32x32x16_bf16(a, b, c, 0, 0, 0);
}

// ---------------- casts ----------------
__global__ void cast_f32_bf16(const float* __restrict__ src, short* __restrict__ dst, int n4) {
    int i = blockIdx.x * blockDim.x + threadIdx.x;
    int stride = gridDim.x * blockDim.x;
    for (; i < n4; i += stride) {
        float4 v = reinterpret_cast<const float4*>(src)[i];
        short4 o;
        o.x = f2bf(v.x); o.y = f2bf(v.y); o.z = f2bf(v.z); o.w = f2bf(v.w);
        reinterpret_cast<short4*>(dst)[i] = o;
    }
}

__global__ void cast_w5(const float* __restrict__ w0, const float* __restrict__ w1,
                        const float* __restrict__ w2, const float* __restrict__ w3,
                        const float* __restrict__ w4,
                        short* __restrict__ o0, short* __restrict__ o1,
                        short* __restrict__ o2, short* __restrict__ o3,
                        short* __restrict__ o4) {
    int z = blockIdx.y;
    const float* s = z == 0 ? w0 : z == 1 ? w1 : z == 2 ? w2 : z == 3 ? w3 : w4;
    short* d = z == 0 ? o0 : z == 1 ? o1 : z == 2 ? o2 : z == 3 ? o3 : o4;
    int i = blockIdx.x * blockDim.x + threadIdx.x;
    float4 v = reinterpret_cast<const float4*>(s)[i];
    short4 o;
    o.x = f2bf(v.x); o.y = f2bf(v.y); o.z = f2bf(v.z); o.w = f2bf(v.w);
    reinterpret_cast<short4*>(d)[i] = o;
}

// ---------------- LDS staging (global_load_lds, pre-swizzled source) ----------------
__device__ __forceinline__ void gload16(const short* g, short* l) {
    __builtin_amdgcn_global_load_lds((const __attribute__((address_space(1))) void*)g,
                                     (__attribute__((address_space(3))) void*)l, 16, 0, 0);
}

__device__ __forceinline__ void stage128x64(short* lds_t, const short* g, int ld, int tid, int w) {
    #pragma unroll
    for (int call = 0; call < 4; ++call) {
        int c = call * 256 + tid;
        int row = c >> 3;
        int sc = (c & 7) ^ (row & 7);
        gload16(g + (size_t)row * ld + sc * 8, lds_t + (size_t)(call * 256 + w * 64) * 8);
    }
}

__device__ __forceinline__ void stage64x64(short* lds_t, const short* g, int ld, int tid, int w) {
    #pragma unroll
    for (int call = 0; call < 2; ++call) {
        int c = call * 256 + tid;
        int row = c >> 3;
        int sc = (c & 7) ^ (row & 7);
        gload16(g + (size_t)row * ld + sc * 8, lds_t + (size_t)(call * 256 + w * 64) * 8);
    }
}

// read one MFMA fragment (8 bf16) from swizzled tile: row, 16B-chunk kc (0..7)
__device__ __forceinline__ s16x8 frag_read(const short* tile, int row, int kc) {
    const char* p = (const char*)tile + row * 128 + (((kc ^ (row & 7)) & 7) << 4);
    return *reinterpret_cast<const s16x8*>(p);
}

// ---------------- projection GEMM: C = A(4096x1024) * W^T, 4 weights ----------------
__global__ __launch_bounds__(256) void gemm4_proj(
    const short* __restrict__ xb,
    const short* __restrict__ w0, const short* __restrict__ w1,
    const short* __restrict__ w2, const short* __restrict__ w3,
    short* __restrict__ o0, short* __restrict__ o1,
    short* __restrict__ o2, short* __restrict__ o3)
{
    __shared__ short sA[128 * 64], sB[128 * 64];
    int tid = threadIdx.x, lane = tid & 63, w = tid >> 6;
    int wrow = w >> 1, wcol = w & 1;
    int z = blockIdx.y;
    const short* W = z == 0 ? w0 : z == 1 ? w1 : z == 2 ? w2 : w3;
    short* outp = z == 0 ? o0 : z == 1 ? o1 : z == 2 ? o2 : o3;
    int r0 = (blockIdx.x >> 3) * 128;
    int c0 = (blockIdx.x & 7) * 128;

    f32x4 zero = {0.f, 0.f, 0.f, 0.f};
    f32x4 acc[4][4];
    #pragma unroll
    for (int i = 0; i < 4; ++i)
        #pragma unroll
        for (int j = 0; j < 4; ++j) acc[i][j] = zero;

    for (int kt = 0; kt < 16; ++kt) {
        __syncthreads();
        stage128x64(sA, xb + (size_t)r0 * CDIM + kt * 64, CDIM, tid, w);
        stage128x64(sB, W + (size_t)c0 * CDIM + kt * 64, CDIM, tid, w);
        __syncthreads();
        #pragma unroll
        for (int ks = 0; ks < 2; ++ks) {
            int kc = ks * 4 + (lane >> 4);
            s16x8 af[4], bfr[4];
            #pragma unroll
            for (int mt = 0; mt < 4; ++mt) af[mt] = frag_read(sA, wrow * 64 + mt * 16 + (lane & 15), kc);
            #pragma unroll
            for (int nt = 0; nt < 4; ++nt) bfr[nt] = frag_read(sB, wcol * 64 + nt * 16 + (lane & 15), kc);
            #pragma unroll
            for (int mt = 0; mt < 4; ++mt)
                #pragma unroll
                for (int nt = 0; nt < 4; ++nt)
                    acc[mt][nt] = __builtin_amdgcn_mfma_f32_16x16x32_bf16(af[mt], bfr[nt], acc[mt][nt], 0, 0, 0);
        }
    }

    bool vt_mode = (z == 2);
    #pragma unroll
    for (int mt = 0; mt < 4; ++mt)
        #pragma unroll
        for (int nt = 0; nt < 4; ++nt)
            #pragma unroll
            for (int jr = 0; jr < 4; ++jr) {
                int gi = r0 + wrow * 64 + mt * 16 + ((lane >> 4) << 2) + jr;
                int gn = c0 + wcol * 64 + nt * 16 + (lane & 15);
                short v = f2bf(acc[mt][nt][jr]);
                int b = gi >> 11, t = gi & 2047, h = gn >> 6, d = gn & 63;
                size_t off;
                if (!vt_mode) off = ((size_t)(b * 16 + h) * TSZ + t) * 64 + d;   // (B,H,T,D)
                else          off = ((size_t)(b * 16 + h) * 64 + d) * TSZ + t;   // (B,H,D,T)
                outp[off] = v;
            }
}

// ---------------- final GEMM: out(f32) = attn(4096x1024 bf16) * Wo^T ----------------
__global__ __launch_bounds__(256) void gemm_final(
    const short* __restrict__ ab, const short* __restrict__ wo, float* __restrict__ out)
{
    __shared__ short sA[128 * 64], sB[128 * 64];
    int tid = threadIdx.x, lane = tid & 63, w = tid >> 6;
    int wrow = w >> 1, wcol = w & 1;
    int r0 = (blockIdx.x >> 3) * 128;
    int c0 = (blockIdx.x & 7) * 128;

    f32x4 zero = {0.f, 0.f, 0.f, 0.f};
    f32x4 acc[4][4];
    #pragma unroll
    for (int i = 0; i < 4; ++i)
        #pragma unroll
        for (int j = 0; j < 4; ++j) acc[i][j] = zero;

    for (int kt = 0; kt < 16; ++kt) {
        __syncthreads();
        stage128x64(sA, ab + (size_t)r0 * CDIM + kt * 64, CDIM, tid, w);
        stage128x64(sB, wo + (size_t)c0 * CDIM + kt * 64, CDIM, tid, w);
        __syncthreads();
        #pragma unroll
        for (int ks = 0; ks < 2; ++ks) {
            int kc = ks * 4 + (lane >> 4);
            s16x8 af[4], bfr[4];
            #pragma unroll
            for (int mt = 0; mt < 4; ++mt) af[mt] = frag_read(sA, wrow * 64 + mt * 16 + (lane & 15), kc);
            #pragma unroll
            for (int nt = 0; nt < 4; ++nt) bfr[nt] = frag_read(sB, wcol * 64 + nt * 16 + (lane & 15), kc);
            #pragma unroll
            for (int mt = 0; mt < 4; ++mt)
                #pragma unroll
                for (int nt = 0; nt < 4; ++nt)
                    acc[mt][nt] = __builtin_amdgcn_mfma_f32_16x16x32_bf16(af[mt], bfr[nt], acc[mt][nt], 0, 0, 0);
        }
    }

    #pragma unroll
    for (int mt = 0; mt < 4; ++mt)
        #pragma unroll
        for (int nt = 0; nt < 4; ++nt)
            #pragma unroll
            for (int jr = 0; jr < 4; ++jr) {
                int gi = r0 + wrow * 64 + mt * 16 + ((lane >> 4) << 2) + jr;
                int gn = c0 + wcol * 64 + nt * 16 + (lane & 15);
                out[(size_t)gi * CDIM + gn] = acc[mt][nt][jr];
            }
}

// ---------------- fused dual-branch flash attention (swapped-QK^T, 32x32 MFMA) ----
// Per wave: 32 q-rows. S^T = mfma(K, Q): C col = q (lane&31), row = key
// (reg&3)+8*(reg>>2)+4*(lane>>5). Lane holds 32 of 64 keys -> in-lane softmax +
// one cross-half shfl. P packed via v_cvt_pk_bf16_f32 + permlane32_swap (T12),
// defer-max rescale (T13), setprio around MFMA clusters (T5).
__global__ __launch_bounds__(256, 2) void attn_fused(
    const short* __restrict__ q, const short* __restrict__ k, const short* __restrict__ kp,
    const short* __restrict__ vt, const float* __restrict__ alphap, short* __restrict__ aout)
{
    __shared__ short sK[2][64 * 64], sKp[2][64 * 64], sV[2][64 * 64];
    int tid = threadIdx.x, lane = tid & 63, w = tid >> 6;
    int h = lane >> 5, l31 = lane & 31;
    int bh = blockIdx.y;
    int qt0 = blockIdx.x * 128;
    const short* Q  = q  + (size_t)bh * TSZ * 64;
    const short* K  = k  + (size_t)bh * TSZ * 64;
    const short* Kp = kp + (size_t)bh * TSZ * 64;
    const short* Vt = vt + (size_t)bh * 64 * TSZ;

    const float SCL = 0.125f;  // 1/sqrt(64); m[] tracked pre-scaled (natural-log domain)

    int qrow = qt0 + w * 32 + l31;
    s16x8 qf[4];
    #pragma unroll
    for (int s = 0; s < 4; ++s)
        qf[s] = *reinterpret_cast<const s16x8*>(Q + (size_t)qrow * 64 + s * 16 + h * 8);

    f32x16 o[2][2];
    #pragma unroll
    for (int br = 0; br < 2; ++br)
        #pragma unroll
        for (int dt = 0; dt < 2; ++dt)
            #pragma unroll
            for (int r = 0; r < 16; ++r) o[br][dt][r] = 0.f;
    float m[2] = {-1e30f, -1e30f}, lsum[2] = {0.f, 0.f};

    // prologue: stage tile 0
    stage64x64(sK[0],  K, 64, tid, w);
    stage64x64(sKp[0], Kp, 64, tid, w);
    stage64x64(sV[0],  Vt, TSZ, tid, w);
    __syncthreads();

    int cur = 0;
    for (int kt = 0; kt < 32; ++kt) {
        if (kt < 31) {
            int t0n = (kt + 1) * 64;
            stage64x64(sK[cur ^ 1],  K  + (size_t)t0n * 64, 64, tid, w);
            stage64x64(sKp[cur ^ 1], Kp + (size_t)t0n * 64, 64, tid, w);
            stage64x64(sV[cur ^ 1],  Vt + t0n, TSZ, tid, w);
        }
        const short* kbuf0 = sK[cur];
        const short* kbuf1 = sKp[cur];
        const short* vbuf  = sV[cur];

        u32x4 pfrag[2][4];
        #pragma unroll
        for (int br = 0; br < 2; ++br) {
            const short* kb = br == 0 ? kbuf0 : kbuf1;
            f32x16 sa0, sa1;
            #pragma unroll
            for (int r = 0; r < 16; ++r) { sa0[r] = 0.f; sa1[r] = 0.f; }
            __builtin_amdgcn_s_setprio(1);
            #pragma unroll
            for (int s = 0; s < 4; ++s) {
                s16x8 af0 = frag_read(kb, l31,      2 * s + h);
                s16x8 af1 = frag_read(kb, 32 + l31, 2 * s + h);
                sa0 = mfma32(af0, qf[s], sa0);
                sa1 = mfma32(af1, qf[s], sa1);
            }
            __builtin_amdgcn_s_setprio(0);

            // row-max (4-way tree) + cross-half exchange
            float t0 = -1e30f, t1 = -1e30f, t2 = -1e30f, t3 = -1e30f;
            #pragma unroll
            for (int r = 0; r < 16; r += 4) {
                t0 = fmaxf(t0, fmaxf(sa0[r],     sa1[r]));
                t1 = fmaxf(t1, fmaxf(sa0[r + 1], sa1[r + 1]));
                t2 = fmaxf(t2, fmaxf(sa0[r + 2], sa1[r + 2]));
                t3 = fmaxf(t3, fmaxf(sa0[r + 3], sa1[r + 3]));
            }
            float pmax = fmaxf(fmaxf(t0, t1), fmaxf(t2, t3));
            pmax = fmaxf(pmax, __shfl_xor(pmax, 32, 64));
            float pmax_s = pmax * SCL;

            // defer-max (T13): rescale only when max grew by > 8 (nat-log)
            if (__any(pmax_s > m[br] + 8.f)) {
                float mnew = fmaxf(m[br], pmax_s);
                float scl = __expf(m[br] - mnew);
                m[br] = mnew;
                lsum[br] *= scl;
                #pragma unroll
                for (int dt = 0; dt < 2; ++dt)
                    #pragma unroll
                    for (int r = 0; r < 16; ++r) o[br][dt][r] *= scl;
            }
            float mS = m[br];

            // P = exp(S*SCL - mS), 4-way partial sums
            float p0 = 0.f, p1 = 0.f, p2 = 0.f, p3 = 0.f;
            #pragma unroll
            for (int r = 0; r < 16; r += 4) {
                sa0[r]     = __expf(fmaf(sa0[r],     SCL, -mS)); p0 += sa0[r];
                sa0[r + 1] = __expf(fmaf(sa0[r + 1], SCL, -mS)); p1 += sa0[r + 1];
                sa0[r + 2] = __expf(fmaf(sa0[r + 2], SCL, -mS)); p2 += sa0[r + 2];
                sa0[r + 3] = __expf(fmaf(sa0[r + 3], SCL, -mS)); p3 += sa0[r + 3];
                sa1[r]     = __expf(fmaf(sa1[r],     SCL, -mS)); p0 += sa1[r];
                sa1[r + 1] = __expf(fmaf(sa1[r + 1], SCL, -mS)); p1 += sa1[r + 1];
                sa1[r + 2] = __expf(fmaf(sa1[r + 2], SCL, -mS)); p2 += sa1[r + 2];
                sa1[r + 3] = __expf(fmaf(sa1[r + 3], SCL, -mS)); p3 += sa1[r + 3];
            }
            float psum = (p0 + p1) + (p2 + p3);
            psum += __shfl_xor(psum, 32, 64);
            lsum[br] += psum;

            // pack P -> bf16 B-frags: cvt_pk + permlane32_swap (T12)
            #pragma unroll
            for (int t = 0; t < 2; ++t) {
                const f32x16* sap = t ? &sa1 : &sa0;
                unsigned pk[8];
                #pragma unroll
                for (int i = 0; i < 8; ++i)
                    pk[i] = cvtpk((*sap)[2 * i], (*sap)[2 * i + 1]);
                u32x2 r02 = __builtin_amdgcn_permlane32_swap(pk[0], pk[2], false, false);
                u32x2 r13 = __builtin_amdgcn_permlane32_swap(pk[1], pk[3], false, false);
                u32x2 r46 = __builtin_amdgcn_permlane32_swap(pk[4], pk[6], false, false);
                u32x2 r57 = __builtin_amdgcn_permlane32_swap(pk[5], pk[7], false, false);
                u32x4 fA, fB;
                fA[0] = r02[0]; fA[1] = r13[0]; fA[2] = r02[1]; fA[3] = r13[1];
                fB[0] = r46[0]; fB[1] = r57[0]; fB[2] = r46[1]; fB[3] = r57[1];
                pfrag[br][2 * t] = fA;
                pfrag[br][2 * t + 1] = fB;
            }
        }

        // PV: O^T[d][q] += V^T[d][key] * P[q][key]; V-frags shared by both branches
        __builtin_amdgcn_s_setprio(1);
        #pragma unroll
        for (int s = 0; s < 4; ++s)
            #pragma unroll
            for (int dt = 0; dt < 2; ++dt) {
                s16x8 vf = frag_read(vbuf, dt * 32 + l31, 2 * s + h);
                o[0][dt] = mfma32(vf, u2s(pfrag[0][s]), o[0][dt]);
                o[1][dt] = mfma32(vf, u2s(pfrag[1][s]), o[1][dt]);
            }
        __builtin_amdgcn_s_setprio(0);

        __syncthreads();   // drain next-tile loads (overlapped) + buffer-reuse barrier
        cur ^= 1;
    }

    // epilogue: out[q][d] = alpha*o0/l0 + (1-alpha)*o1/l1, written to (B,T,C)
    float alpha = alphap[0];
    float a0 = alpha / lsum[0];
    float a1 = (1.f - alpha) / lsum[1];
    int b = bh >> 4, hh = bh & 15;
    int t = qt0 + w * 32 + l31;
    size_t rowbase = ((size_t)(b * TSZ + t)) * CDIM + hh * 64;
    #pragma unroll
    for (int dt = 0; dt < 2; ++dt)
        #pragma unroll
        for (int g = 0; g < 4; ++g) {
            short4 v4;
            #pragma unroll
            for (int j = 0; j < 4; ++j) {
                int r = 4 * g + j;   // d = j + 8g + 4h + 32dt
                float v = a0 * o[0][dt][r] + a1 * o[1][dt][r];
                ((short*)&v4)[j] = f2bf(v);
            }
            *reinterpret_cast<short4*>(aout + rowbase + dt * 32 + g * 8 + h * 4) = v4;
        }
}

// ---------------- host ----------------
extern "C" void kernel_launch(void* const* d_in, const int* in_sizes, int n_in,
                              void* d_out, int out_size, void* d_ws, size_t ws_size,
                              hipStream_t stream)
{
    const float* x     = (const float*)d_in[0];
    const float* WQ    = (const float*)d_in[1];
    const float* WK    = (const float*)d_in[2];
    const float* WV    = (const float*)d_in[3];
    const float* WKp   = (const float*)d_in[4];
    const float* WO    = (const float*)d_in[5];
    const float* alpha = (const float*)d_in[6];
    float* out = (float*)d_out;

    char* ws = (char*)d_ws;
    const size_t MB = 1024 * 1024;
    short* xb   = (short*)(ws + 0);        // 8 MB  x bf16
    short* wqb  = (short*)(ws + 8 * MB);   // 2 MB each
    short* wkb  = (short*)(ws + 10 * MB);
    short* wvb  = (short*)(ws + 12 * MB);
    short* wkpb = (short*)(ws + 14 * MB);
    short* wob  = (short*)(ws + 16 * MB);
    short* qb   = (short*)(ws + 18 * MB);  // 8 MB each, (B,H,T,D)
    short* kb   = (short*)(ws + 26 * MB);
    short* kpb  = (short*)(ws + 34 * MB);
    short* vtb  = (short*)(ws + 42 * MB);  // (B,H,D,T)
    short* anb  = (short*)(ws + 50 * MB);  // attention out, (B,T,C) bf16

    cast_f32_bf16<<<2048, 256, 0, stream>>>(x, xb, (TSZ * 2 * CDIM) / 4);
    cast_w5<<<dim3(1024, 5), 256, 0, stream>>>(WQ, WK, WV, WKp, WO,
                                               wqb, wkb, wvb, wkpb, wob);

    gemm4_proj<<<dim3(256, 4), 256, 0, stream>>>(xb, wqb, wkb, wvb, wkpb, qb, kb, vtb, kpb);
    attn_fused<<<dim3(16, 32), 256, 0, stream>>>(qb, kb, kpb, vtb, alpha, anb);
    gemm_final<<<dim3(256), 256, 0, stream>>>(anb, wob, out);
}